// Round 9
// baseline (146.168 us; speedup 1.0000x reference)
//
#include <hip/hip_runtime.h>
#include <hip/hip_bf16.h>
#include <stdint.h>
#include <stddef.h>

#define TT 4096
#define CC 1024
#define NFD 1024
#define N3 3072
#define JSPLIT 17  // j-tile chunk boundary for split-K PV (balances both chunks at <=60 K-steps)

typedef __bf16 bf16;
typedef __bf16 bf16x8 __attribute__((ext_vector_type(8)));
typedef __bf16 bf16x4 __attribute__((ext_vector_type(4)));
typedef float f32x4 __attribute__((ext_vector_type(4)));

typedef const __attribute__((address_space(1))) unsigned char gl_u8;
typedef __attribute__((address_space(3))) unsigned char lds_u8;

__device__ __forceinline__ void glds16(const void* g, void* l) {
  __builtin_amdgcn_global_load_lds((gl_u8*)g, (lds_u8*)l, 16, 0, 0);
}

// Stage a 128x32 bf16 tile (row-major, ld in elements) into linear LDS [128][32].
// 2 glds16 per thread (4 per thread per A+B tile pair) -> vmcnt counts below.
__device__ __forceinline__ void stage128x32(const bf16* __restrict__ src, int ld, bf16* lds, int tid) {
  const int lane = tid & 63;
  const int w = tid >> 6;
#pragma unroll
  for (int p = 0; p < 2; ++p) {
    const int lbyte = w * 2048 + p * 1024;              // wave-uniform LDS base (bytes)
    const int row = (lbyte >> 6) + (lane >> 2);         // this lane's 16B lands at row, k8
    const int kel = (lane & 3) << 3;
    glds16(src + row * ld + kel, (char*)lds + lbyte);
  }
}

// ---------- 4-wave core: 128x128 tile, BK=32, 3-buffer ring, counted vmcnt ----------
// Protocol (race-safe per-wave): iteration ks stages tile ks+2 (4 loads/thread),
// waits OWN vmcnt(8) (tiles ks+1,ks+2 may remain in flight; tile ks retired),
// then s_barrier => ALL waves' tile-ks loads are globally complete. Second
// barrier protects buffer reuse (tile ks+3 overwrites buf[ks%3] next iteration).
// No vmcnt(0) drain in the main loop -> prefetch latency hidden under 2 phases.
// As/Bs each hold 3*128*32 elements (24 KB); 48 KB total -> 3 blocks/CU.
__device__ __forceinline__ void gemm_core(const bf16* __restrict__ A, const bf16* __restrict__ B,
                                          int lda, int ldb, int ksteps,
                                          bf16* As, bf16* Bs, int tid, f32x4 (&acc)[4][4]) {
  const int lane = tid & 63;
  const int w = tid >> 6;
  const int wm = (w >> 1) * 64;
  const int wn = (w & 1) * 64;
  const int lrow = lane & 15;
  const int lko = (lane >> 4) * 8;
  // prologue: stage tiles 0 and 1
  stage128x32(A, lda, As, tid);
  stage128x32(B, ldb, Bs, tid);
  if (ksteps > 1) {
    stage128x32(A + 32, lda, As + 4096, tid);
    stage128x32(B + 32, ldb, Bs + 4096, tid);
  }
  for (int ks = 0; ks < ksteps; ++ks) {
    const int cur = ks % 3;
    if (ks + 2 < ksteps) {
      const int nx2 = (ks + 2) % 3;
      stage128x32(A + (size_t)(ks + 2) * 32, lda, As + nx2 * 4096, tid);
      stage128x32(B + (size_t)(ks + 2) * 32, ldb, Bs + nx2 * 4096, tid);
      asm volatile("s_waitcnt vmcnt(8)" ::: "memory");   // tiles ks+1,ks+2 in flight
    } else if (ks + 1 < ksteps) {
      asm volatile("s_waitcnt vmcnt(4)" ::: "memory");   // tile ks+1 in flight
    } else {
      asm volatile("s_waitcnt vmcnt(0)" ::: "memory");
    }
    __builtin_amdgcn_s_barrier();   // all waves passed their vmcnt -> tile ks complete
    const bf16* Ac = As + cur * 4096;
    const bf16* Bc = Bs + cur * 4096;
    bf16x8 af[4], bfr[4];
#pragma unroll
    for (int i = 0; i < 4; ++i)
      af[i] = *(const bf16x8*)(Ac + (wm + i * 16 + lrow) * 32 + lko);
#pragma unroll
    for (int i = 0; i < 4; ++i)
      bfr[i] = *(const bf16x8*)(Bc + (wn + i * 16 + lrow) * 32 + lko);
#pragma unroll
    for (int mi = 0; mi < 4; ++mi)
#pragma unroll
      for (int ni = 0; ni < 4; ++ni)
        acc[mi][ni] = __builtin_amdgcn_mfma_f32_16x16x32_bf16(af[mi], bfr[ni], acc[mi][ni], 0, 0, 0);
    __builtin_amdgcn_s_barrier();   // readers done before buf[ks%3] is overwritten
  }
}

// ---- K0: merged prep. blocks [0,2048): x fp32->bf16. blocks [2048,2816): W transpose. ----
__global__ __launch_bounds__(256) void k_prep(const float* __restrict__ x, bf16* __restrict__ xb,
                                              const float* __restrict__ Wsrc, bf16* __restrict__ WbT) {
  __shared__ float Ls[64][68];
  const int tid = threadIdx.x;
  if (blockIdx.x < 2048) {
    int idx = (blockIdx.x * 256 + tid) * 8;
    f32x4 a = *(const f32x4*)(x + idx);
    f32x4 b = *(const f32x4*)(x + idx + 4);
    bf16x8 o;
#pragma unroll
    for (int j = 0; j < 4; ++j) { o[j] = (bf16)a[j]; o[4 + j] = (bf16)b[j]; }
    *(bf16x8*)(xb + idx) = o;
    return;
  }
  const int bid = blockIdx.x - 2048;
  const int n0 = (bid % 48) * 64;
  const int c0 = (bid / 48) * 64;
#pragma unroll
  for (int qq = 0; qq < 4; ++qq) {
    int lin = qq * 1024 + tid * 4;
    int r = lin >> 6, cc = lin & 63;
    f32x4 v = *(const f32x4*)(Wsrc + (size_t)(c0 + r) * N3 + n0 + cc);
#pragma unroll
    for (int j = 0; j < 4; ++j) Ls[r][cc + j] = v[j];
  }
  __syncthreads();
#pragma unroll
  for (int qq = 0; qq < 4; ++qq) {
    int lin = qq * 1024 + tid * 4;
    int nr = lin >> 6, cc = lin & 63;
    bf16x4 o;
#pragma unroll
    for (int j = 0; j < 4; ++j) o[j] = (bf16)Ls[cc + j][nr];
    *(bf16x4*)(WbT + (size_t)(n0 + nr) * CC + c0 + cc) = o;
  }
}

// ---- K1: qkv = xb @ WbT^T + b ; writes q,k natural [t][c] and v transposed [d][t] ----
__global__ __launch_bounds__(256, 2) void k_qkv(const bf16* __restrict__ xb, const bf16* __restrict__ wbt,
                                                const float* __restrict__ bias,
                                                bf16* __restrict__ q, bf16* __restrict__ k,
                                                bf16* __restrict__ vT) {
  __shared__ bf16 As[3 * 128 * 32], Bs[3 * 128 * 32];
  const int tid = threadIdx.x;
  const int m0 = blockIdx.y * 128;
  const int n0 = blockIdx.x * 128;
  f32x4 acc[4][4];
#pragma unroll
  for (int i = 0; i < 4; ++i)
#pragma unroll
    for (int j = 0; j < 4; ++j) acc[i][j] = (f32x4){0.f, 0.f, 0.f, 0.f};

  gemm_core(xb + (size_t)m0 * CC, wbt + (size_t)n0 * CC, CC, CC, CC / 32, As, Bs, tid, acc);

  const int lane = tid & 63;
  const int w = tid >> 6;
  const int wm = (w >> 1) * 64, wn = (w & 1) * 64;
  const int seg = n0 >> 10;  // 0:q 1:k 2:v
#pragma unroll
  for (int mi = 0; mi < 4; ++mi) {
    const int tB = m0 + wm + mi * 16 + ((lane >> 4) << 2);
#pragma unroll
    for (int ni = 0; ni < 4; ++ni) {
      const int n = n0 + wn + ni * 16 + (lane & 15);
      const float bb = bias[n];
      f32x4 a = acc[mi][ni];
      if (seg == 2) {
        bf16x4 pv;
#pragma unroll
        for (int r = 0; r < 4; ++r) pv[r] = (bf16)(a[r] + bb);
        *(bf16x4*)(vT + (size_t)(n - 2048) * TT + tB) = pv;  // vT[d][t]
      } else {
        bf16* dst = (seg == 0) ? q : k;
        const int nl = n & 1023;
#pragma unroll
        for (int r = 0; r < 4; ++r) dst[(size_t)(tB + r) * NFD + nl] = (bf16)(a[r] + bb);
      }
    }
  }
}

// ---- K2: P' = exp(mask(q @ k^T / 32)) as bf16; row sums l via atomicAdd ----
__global__ __launch_bounds__(256, 2) void k_scores(const bf16* __restrict__ q, const bf16* __restrict__ kk,
                                                   bf16* __restrict__ P, float* __restrict__ l,
                                                   const int* __restrict__ npadd_p) {
  const int jt = blockIdx.x, it = blockIdx.y;
  const int np = *npadd_p;
  const int jt0 = np >> 7;
  if (jt > it || jt < jt0) return;  // fully-masked tile: never read by K3
  __shared__ bf16 As[3 * 128 * 32], Bs[3 * 128 * 32];
  const int tid = threadIdx.x;
  f32x4 acc[4][4];
#pragma unroll
  for (int i = 0; i < 4; ++i)
#pragma unroll
    for (int j = 0; j < 4; ++j) acc[i][j] = (f32x4){0.f, 0.f, 0.f, 0.f};

  gemm_core(q + (size_t)it * 128 * CC, kk + (size_t)jt * 128 * CC, CC, CC, CC / 32, As, Bs, tid, acc);

  const int lane = tid & 63;
  const int w = tid >> 6;
  const int wm = (w >> 1) * 64, wn = (w & 1) * 64;
  const float scale = 0.03125f;  // 1/sqrt(1024)
#pragma unroll
  for (int mi = 0; mi < 4; ++mi) {
    const int iB = it * 128 + wm + mi * 16 + ((lane >> 4) << 2);
    float rs[4] = {0.f, 0.f, 0.f, 0.f};
#pragma unroll
    for (int ni = 0; ni < 4; ++ni) {
      const int j = jt * 128 + wn + ni * 16 + (lane & 15);
      f32x4 a = acc[mi][ni];
#pragma unroll
      for (int r = 0; r < 4; ++r) {
        const int i = iB + r;
        float p = 0.f;
        if (j <= i && j >= np && i >= np) p = __expf(a[r] * scale);
        const bf16 pb = (bf16)p;
        P[(size_t)i * TT + j] = pb;
        rs[r] += (float)pb;
      }
    }
#pragma unroll
    for (int r = 0; r < 4; ++r) {
      float v = rs[r];
      v += __shfl_xor(v, 1);
      v += __shfl_xor(v, 2);
      v += __shfl_xor(v, 4);
      v += __shfl_xor(v, 8);
      if ((lane & 15) == 0) atomicAdd(&l[iB + r], v);
    }
  }
}

// ---- K3a: 2-way split-K PV, NO atomics. chunk 0: j-tiles [jt0, 17); chunk 1: [17, it+1).
//      Each chunk writes its own bf16 partial buffer with plain stores. ----
__global__ __launch_bounds__(256, 2) void k_pvc(const bf16* __restrict__ P, const bf16* __restrict__ vT,
                                                bf16* __restrict__ part0, bf16* __restrict__ part1,
                                                const int* __restrict__ npadd_p) {
  const int c = blockIdx.x;       // 0..1
  const int it = blockIdx.y;      // 0..31
  const int d0 = blockIdx.z * 128;
  const int np = *npadd_p;
  const int jt0 = np >> 7;
  int jlo, jhi;
  if (c == 0) { jlo = jt0;                      jhi = min(JSPLIT, it + 1); }
  else        { jlo = max(JSPLIT, jt0);         jhi = it + 1; }
  if (jlo >= jhi) return;

  __shared__ bf16 As[3 * 128 * 32], Bs[3 * 128 * 32];
  const int tid = threadIdx.x;
  f32x4 acc[4][4];
#pragma unroll
  for (int i = 0; i < 4; ++i)
#pragma unroll
    for (int j = 0; j < 4; ++j) acc[i][j] = (f32x4){0.f, 0.f, 0.f, 0.f};

  gemm_core(P + (size_t)it * 128 * TT + (size_t)jlo * 128,
            vT + (size_t)d0 * TT + (size_t)jlo * 128,
            TT, TT, (jhi - jlo) * 4, As, Bs, tid, acc);

  bf16* __restrict__ part = (c == 0) ? part0 : part1;
  const int lane = tid & 63;
  const int w = tid >> 6;
  const int wm = (w >> 1) * 64, wn = (w & 1) * 64;
#pragma unroll
  for (int mi = 0; mi < 4; ++mi) {
    const int iB = it * 128 + wm + mi * 16 + ((lane >> 4) << 2);
#pragma unroll
    for (int ni = 0; ni < 4; ++ni) {
      const int d = d0 + wn + ni * 16 + (lane & 15);
      f32x4 a = acc[mi][ni];
#pragma unroll
      for (int r = 0; r < 4; ++r)
        part[(size_t)(iB + r) * NFD + d] = (bf16)a[r];
    }
  }
}

// ---- K3b: y = (part0 [+ part1]) / l for i>=np else 0 ----
__global__ __launch_bounds__(256) void k_norm(const bf16* __restrict__ part0, const bf16* __restrict__ part1,
                                              const float* __restrict__ l, float* __restrict__ y,
                                              const int* __restrict__ npadd_p) {
  const int idx = (blockIdx.x * 256 + threadIdx.x) * 8;
  const int i = idx >> 10;  // / NFD
  const int np = *npadd_p;
  const int jt0 = np >> 7;
  const int it = i >> 7;
  float s[8] = {0.f, 0.f, 0.f, 0.f, 0.f, 0.f, 0.f, 0.f};
  float inv = 0.f;
  if (i >= np) {
    inv = 1.0f / l[i];
    if (min(JSPLIT, it + 1) > jt0) {          // chunk-0 partial exists for this row
      bf16x8 a = *(const bf16x8*)(part0 + idx);
#pragma unroll
      for (int j = 0; j < 8; ++j) s[j] += (float)a[j];
    }
    if (it + 1 > max(JSPLIT, jt0)) {          // chunk-1 partial exists for this row
      bf16x8 b = *(const bf16x8*)(part1 + idx);
#pragma unroll
      for (int j = 0; j < 8; ++j) s[j] += (float)b[j];
    }
  }
  f32x4 o0, o1;
#pragma unroll
  for (int j = 0; j < 4; ++j) { o0[j] = s[j] * inv; o1[j] = s[4 + j] * inv; }
  *(f32x4*)(y + idx) = o0;
  *(f32x4*)(y + idx + 4) = o1;
}

extern "C" void kernel_launch(void* const* d_in, const int* in_sizes, int n_in,
                              void* d_out, int out_size, void* d_ws, size_t ws_size,
                              hipStream_t stream) {
  const float* x = (const float*)d_in[0];
  const float* W = (const float*)d_in[1];
  const float* b = (const float*)d_in[2];
  const int* npadd = (const int*)d_in[3];
  float* y = (float*)d_out;

  char* ws = (char*)d_ws;
  const size_t MB = 1u << 20;
  bf16* q  = (bf16*)(ws + 0 * MB);          // 8 MB  [T][C]   (dead after k_scores)
  bf16* kk = (bf16*)(ws + 8 * MB);          // 8 MB  [T][C]   (dead after k_scores)
  bf16* part0 = (bf16*)(ws + 0 * MB);       // 8 MB [T][D] bf16, overlays q
  bf16* part1 = (bf16*)(ws + 8 * MB);       // 8 MB [T][D] bf16, overlays kk
  bf16* vT = (bf16*)(ws + 16 * MB);         // 8 MB  [D][T]
  float* l = (float*)(ws + 24 * MB);        // 16 KB
  bf16* P  = (bf16*)(ws + 24 * MB + 65536); // 32 MB [T][T]
  bf16* xb = P;                              // overlap: dead before K2 writes P
  bf16* WbT = (bf16*)((char*)P + 8 * MB);    // 6 MB, also dead before K2

  // K0: convert x + transpose/convert W (merged, independent regions)
  k_prep<<<dim3(2048 + 768), 256, 0, stream>>>(x, xb, W, WbT);
  // K1: QKV projection
  k_qkv<<<dim3(N3 / 128, TT / 128), 256, 0, stream>>>(xb, WbT, b, q, kk, vT);
  // K2: masked exp-scores + row sums
  hipMemsetAsync(l, 0, TT * sizeof(float), stream);
  k_scores<<<dim3(TT / 128, TT / 128), 256, 0, stream>>>(q, kk, P, l, npadd);
  // K3: 2-way split-K PV into bf16 partials (no atomics)
  k_pvc<<<dim3(2, TT / 128, NFD / 128), 256, 0, stream>>>(P, vT, part0, part1, npadd);
  // K3b: sum partials + normalize
  k_norm<<<dim3((TT * NFD) / (256 * 8)), 256, 0, stream>>>(part0, part1, l, y, npadd);
}

// Round 10
// 128.479 us; speedup vs baseline: 1.1377x; 1.1377x over previous
//
#include <hip/hip_runtime.h>
#include <hip/hip_bf16.h>
#include <stdint.h>
#include <stddef.h>

#define TT 4096
#define CC 1024
#define NFD 1024
#define N3 3072
#define JSPLIT 17  // j-tile chunk boundary for split-K PV

typedef __bf16 bf16;
typedef __bf16 bf16x8 __attribute__((ext_vector_type(8)));
typedef __bf16 bf16x4 __attribute__((ext_vector_type(4)));
typedef float f32x4 __attribute__((ext_vector_type(4)));

typedef const __attribute__((address_space(1))) unsigned char gl_u8;
typedef __attribute__((address_space(3))) unsigned char lds_u8;

__device__ __forceinline__ void glds16(const void* g, void* l) {
  __builtin_amdgcn_global_load_lds((gl_u8*)g, (lds_u8*)l, 16, 0, 0);
}

// Stage a 128x32 bf16 tile (row-major, ld in elements) into linear LDS [128][32].
__device__ __forceinline__ void stage128x32(const bf16* __restrict__ src, int ld, bf16* lds, int tid) {
  const int lane = tid & 63;
  const int w = tid >> 6;
#pragma unroll
  for (int p = 0; p < 2; ++p) {
    const int lbyte = w * 2048 + p * 1024;              // wave-uniform LDS base (bytes)
    const int row = (lbyte >> 6) + (lane >> 2);         // this lane's 16B lands at row, k8
    const int kel = (lane & 3) << 3;
    glds16(src + row * ld + kel, (char*)lds + lbyte);
  }
}

// ---------- R6 core (best measured): 128x128, BK=32, 2-buffer, 1 barrier/step ----------
__device__ __forceinline__ void gemm_core(const bf16* __restrict__ A, const bf16* __restrict__ B,
                                          int lda, int ldb, int ksteps,
                                          bf16* As, bf16* Bs, int tid, f32x4 (&acc)[4][4]) {
  const int lane = tid & 63;
  const int w = tid >> 6;
  const int wm = (w >> 1) * 64;
  const int wn = (w & 1) * 64;
  const int lrow = lane & 15;
  const int lko = (lane >> 4) * 8;
  stage128x32(A, lda, As, tid);
  stage128x32(B, ldb, Bs, tid);
  __syncthreads();
  for (int ks = 0; ks < ksteps; ++ks) {
    const bf16* Ac = As + (ks & 1) * 4096;
    const bf16* Bc = Bs + (ks & 1) * 4096;
    if (ks + 1 < ksteps) {
      stage128x32(A + (ks + 1) * 32, lda, As + ((ks + 1) & 1) * 4096, tid);
      stage128x32(B + (ks + 1) * 32, ldb, Bs + ((ks + 1) & 1) * 4096, tid);
    }
    bf16x8 af[4], bfr[4];
#pragma unroll
    for (int i = 0; i < 4; ++i)
      af[i] = *(const bf16x8*)(Ac + (wm + i * 16 + lrow) * 32 + lko);
#pragma unroll
    for (int i = 0; i < 4; ++i)
      bfr[i] = *(const bf16x8*)(Bc + (wn + i * 16 + lrow) * 32 + lko);
#pragma unroll
    for (int mi = 0; mi < 4; ++mi)
#pragma unroll
      for (int ni = 0; ni < 4; ++ni)
        acc[mi][ni] = __builtin_amdgcn_mfma_f32_16x16x32_bf16(af[mi], bfr[ni], acc[mi][ni], 0, 0, 0);
    __syncthreads();
  }
}

// ---- K0: merged prep. blocks [0,2048): x fp32->bf16. blocks [2048,2816): W transpose. ----
__global__ __launch_bounds__(256) void k_prep(const float* __restrict__ x, bf16* __restrict__ xb,
                                              const float* __restrict__ Wsrc, bf16* __restrict__ WbT) {
  __shared__ float Ls[64][68];
  const int tid = threadIdx.x;
  if (blockIdx.x < 2048) {
    int idx = (blockIdx.x * 256 + tid) * 8;
    f32x4 a = *(const f32x4*)(x + idx);
    f32x4 b = *(const f32x4*)(x + idx + 4);
    bf16x8 o;
#pragma unroll
    for (int j = 0; j < 4; ++j) { o[j] = (bf16)a[j]; o[4 + j] = (bf16)b[j]; }
    *(bf16x8*)(xb + idx) = o;
    return;
  }
  const int bid = blockIdx.x - 2048;
  const int n0 = (bid % 48) * 64;
  const int c0 = (bid / 48) * 64;
#pragma unroll
  for (int qq = 0; qq < 4; ++qq) {
    int lin = qq * 1024 + tid * 4;
    int r = lin >> 6, cc = lin & 63;
    f32x4 v = *(const f32x4*)(Wsrc + (size_t)(c0 + r) * N3 + n0 + cc);
#pragma unroll
    for (int j = 0; j < 4; ++j) Ls[r][cc + j] = v[j];
  }
  __syncthreads();
#pragma unroll
  for (int qq = 0; qq < 4; ++qq) {
    int lin = qq * 1024 + tid * 4;
    int nr = lin >> 6, cc = lin & 63;
    bf16x4 o;
#pragma unroll
    for (int j = 0; j < 4; ++j) o[j] = (bf16)Ls[cc + j][nr];
    *(bf16x4*)(WbT + (size_t)(n0 + nr) * CC + c0 + cc) = o;
  }
}

// ---- K1: qkv = xb @ WbT^T + b ; writes q,k natural [t][c] and v transposed [d][t] ----
__global__ __launch_bounds__(256, 2) void k_qkv(const bf16* __restrict__ xb, const bf16* __restrict__ wbt,
                                                const float* __restrict__ bias,
                                                bf16* __restrict__ q, bf16* __restrict__ k,
                                                bf16* __restrict__ vT) {
  __shared__ bf16 As[2 * 128 * 32], Bs[2 * 128 * 32];
  const int tid = threadIdx.x;
  const int m0 = blockIdx.y * 128;
  const int n0 = blockIdx.x * 128;
  f32x4 acc[4][4];
#pragma unroll
  for (int i = 0; i < 4; ++i)
#pragma unroll
    for (int j = 0; j < 4; ++j) acc[i][j] = (f32x4){0.f, 0.f, 0.f, 0.f};

  gemm_core(xb + (size_t)m0 * CC, wbt + (size_t)n0 * CC, CC, CC, CC / 32, As, Bs, tid, acc);

  const int lane = tid & 63;
  const int w = tid >> 6;
  const int wm = (w >> 1) * 64, wn = (w & 1) * 64;
  const int seg = n0 >> 10;  // 0:q 1:k 2:v
#pragma unroll
  for (int mi = 0; mi < 4; ++mi) {
    const int tB = m0 + wm + mi * 16 + ((lane >> 4) << 2);
#pragma unroll
    for (int ni = 0; ni < 4; ++ni) {
      const int n = n0 + wn + ni * 16 + (lane & 15);
      const float bb = bias[n];
      f32x4 a = acc[mi][ni];
      if (seg == 2) {
        bf16x4 pv;
#pragma unroll
        for (int r = 0; r < 4; ++r) pv[r] = (bf16)(a[r] + bb);
        *(bf16x4*)(vT + (size_t)(n - 2048) * TT + tB) = pv;  // vT[d][t]
      } else {
        bf16* dst = (seg == 0) ? q : k;
        const int nl = n & 1023;
#pragma unroll
        for (int r = 0; r < 4; ++r) dst[(size_t)(tB + r) * NFD + nl] = (bf16)(a[r] + bb);
      }
    }
  }
}

// ---- K2: P' = exp(mask(q @ k^T / 32)) as bf16; row sums l via atomicAdd.
//      1D compact triangular grid (528 blocks), band-major (it,jt) enumeration,
//      XCD-chunked swizzle: each XCD gets a contiguous lin-range whose q-tiles
//      (~2.2MB) + k-band (2MB) fit its 4MB L2 -> staged loads hit L2, shorter
//      barrier drains. ----
__global__ __launch_bounds__(256, 2) void k_scores(const bf16* __restrict__ q, const bf16* __restrict__ kk,
                                                   bf16* __restrict__ P, float* __restrict__ l,
                                                   const int* __restrict__ npadd_p) {
  // XCD chunk swizzle: 528 = 8 * 66; physical XCD ~ blockIdx%8 gets lin [66*xcd, 66*(xcd+1))
  const int id = blockIdx.x;
  const int lin = (id & 7) * 66 + (id >> 3);
  // band-major triangular mapping: band b holds jt in [8b, 8b+8), it in [jt, 32)
  int band, rem;
  if (lin < 228)      { band = 0; rem = lin; }
  else if (lin < 392) { band = 1; rem = lin - 228; }
  else if (lin < 492) { band = 2; rem = lin - 392; }
  else                { band = 3; rem = lin - 492; }
  int it, jt;
  if (rem < 28) {  // triangular head: it' = 0..6, row it' has it'+1 entries
    int itp = (int)((sqrtf(8.0f * (float)rem + 1.0f) - 1.0f) * 0.5f);
    while ((itp + 1) * (itp + 2) / 2 <= rem) ++itp;
    while (itp * (itp + 1) / 2 > rem) --itp;
    it = band * 8 + itp;
    jt = band * 8 + (rem - itp * (itp + 1) / 2);
  } else {         // rect body: it' = 7.., 8 entries per row
    const int rem2 = rem - 28;
    it = band * 8 + 7 + (rem2 >> 3);
    jt = band * 8 + (rem2 & 7);
  }
  const int np = *npadd_p;
  const int jt0 = np >> 7;
  if (jt < jt0) return;  // fully-masked tile (jt<=it by construction)

  __shared__ bf16 As[2 * 128 * 32], Bs[2 * 128 * 32];
  const int tid = threadIdx.x;
  f32x4 acc[4][4];
#pragma unroll
  for (int i = 0; i < 4; ++i)
#pragma unroll
    for (int j = 0; j < 4; ++j) acc[i][j] = (f32x4){0.f, 0.f, 0.f, 0.f};

  gemm_core(q + (size_t)it * 128 * CC, kk + (size_t)jt * 128 * CC, CC, CC, CC / 32, As, Bs, tid, acc);

  const int lane = tid & 63;
  const int w = tid >> 6;
  const int wm = (w >> 1) * 64, wn = (w & 1) * 64;
  const float scale = 0.03125f;  // 1/sqrt(1024)
#pragma unroll
  for (int mi = 0; mi < 4; ++mi) {
    const int iB = it * 128 + wm + mi * 16 + ((lane >> 4) << 2);
    float rs[4] = {0.f, 0.f, 0.f, 0.f};
#pragma unroll
    for (int ni = 0; ni < 4; ++ni) {
      const int j = jt * 128 + wn + ni * 16 + (lane & 15);
      f32x4 a = acc[mi][ni];
#pragma unroll
      for (int r = 0; r < 4; ++r) {
        const int i = iB + r;
        float p = 0.f;
        if (j <= i && j >= np && i >= np) p = __expf(a[r] * scale);
        const bf16 pb = (bf16)p;
        P[(size_t)i * TT + j] = pb;
        rs[r] += (float)pb;
      }
    }
#pragma unroll
    for (int r = 0; r < 4; ++r) {
      float v = rs[r];
      v += __shfl_xor(v, 1);
      v += __shfl_xor(v, 2);
      v += __shfl_xor(v, 4);
      v += __shfl_xor(v, 8);
      if ((lane & 15) == 0) atomicAdd(&l[iB + r], v);
    }
  }
}

// ---- K3a: 2-way split-K PV, no atomics. chunk 0: [jt0, min(17,it+1)); chunk 1: [max(17,jt0), it+1).
//      Sole-writer blocks apply 1/l (final after k_scores) and write y fp32 directly;
//      others write bf16 partials summed by k_norm. ----
__global__ __launch_bounds__(256, 2) void k_pvc(const bf16* __restrict__ P, const bf16* __restrict__ vT,
                                                bf16* __restrict__ part0, bf16* __restrict__ part1,
                                                const float* __restrict__ l, float* __restrict__ y,
                                                const int* __restrict__ npadd_p) {
  const int c = blockIdx.x;       // 0..1
  const int it = blockIdx.y;      // 0..31
  const int d0 = blockIdx.z * 128;
  const int np = *npadd_p;
  const int jt0 = np >> 7;
  int jlo, jhi;
  if (c == 0) { jlo = jt0;              jhi = min(JSPLIT, it + 1); }
  else        { jlo = max(JSPLIT, jt0); jhi = it + 1; }
  if (jlo >= jhi) return;

  __shared__ bf16 As[2 * 128 * 32], Bs[2 * 128 * 32];
  const int tid = threadIdx.x;
  f32x4 acc[4][4];
#pragma unroll
  for (int i = 0; i < 4; ++i)
#pragma unroll
    for (int j = 0; j < 4; ++j) acc[i][j] = (f32x4){0.f, 0.f, 0.f, 0.f};

  gemm_core(P + (size_t)it * 128 * TT + (size_t)jlo * 128,
            vT + (size_t)d0 * TT + (size_t)jlo * 128,
            TT, TT, (jhi - jlo) * 4, As, Bs, tid, acc);

  const int lane = tid & 63;
  const int w = tid >> 6;
  const int wm = (w >> 1) * 64, wn = (w & 1) * 64;
  // sole-writer: this chunk covers the row's entire valid j range [jt0, it+1)
  const bool sole = (c == 0) ? (jhi == it + 1) : (jlo == jt0);
  if (sole) {
#pragma unroll
    for (int mi = 0; mi < 4; ++mi) {
      const int iB = it * 128 + wm + mi * 16 + ((lane >> 4) << 2);
      float inv4[4];
#pragma unroll
      for (int r = 0; r < 4; ++r) {
        const int i = iB + r;
        inv4[r] = (i >= np) ? (1.0f / l[i]) : 0.0f;  // i>=np => l>0 (diagonal term)
      }
#pragma unroll
      for (int ni = 0; ni < 4; ++ni) {
        const int d = d0 + wn + ni * 16 + (lane & 15);
        f32x4 a = acc[mi][ni];
#pragma unroll
        for (int r = 0; r < 4; ++r)
          y[(size_t)(iB + r) * NFD + d] = a[r] * inv4[r];
      }
    }
  } else {
    bf16* __restrict__ part = (c == 0) ? part0 : part1;
#pragma unroll
    for (int mi = 0; mi < 4; ++mi) {
      const int iB = it * 128 + wm + mi * 16 + ((lane >> 4) << 2);
#pragma unroll
      for (int ni = 0; ni < 4; ++ni) {
        const int d = d0 + wn + ni * 16 + (lane & 15);
        f32x4 a = acc[mi][ni];
#pragma unroll
        for (int r = 0; r < 4; ++r)
          part[(size_t)(iB + r) * NFD + d] = (bf16)a[r];
      }
    }
  }
}

// ---- K3b: finalize non-sole rows (it>=JSPLIT when jt0<JSPLIT): y=(part0+part1)/l.
//      Pad rows (i<np): write 0. Sole rows: already written by k_pvc -> exit. ----
__global__ __launch_bounds__(256) void k_norm(const bf16* __restrict__ part0, const bf16* __restrict__ part1,
                                              const float* __restrict__ l, float* __restrict__ y,
                                              const int* __restrict__ npadd_p) {
  const int idx = (blockIdx.x * 256 + threadIdx.x) * 8;
  const int i = idx >> 10;  // / NFD
  const int np = *npadd_p;
  const int jt0 = np >> 7;
  const int it = i >> 7;
  if (i < np) {
    f32x4 z = (f32x4){0.f, 0.f, 0.f, 0.f};
    *(f32x4*)(y + idx) = z;
    *(f32x4*)(y + idx + 4) = z;
    return;
  }
  if ((it + 1 <= JSPLIT) || (jt0 >= JSPLIT)) return;  // sole-writer row: y already final
  const float inv = 1.0f / l[i];
  bf16x8 a = *(const bf16x8*)(part0 + idx);
  bf16x8 b = *(const bf16x8*)(part1 + idx);
  f32x4 o0, o1;
#pragma unroll
  for (int j = 0; j < 4; ++j) {
    o0[j] = ((float)a[j] + (float)b[j]) * inv;
    o1[j] = ((float)a[4 + j] + (float)b[4 + j]) * inv;
  }
  *(f32x4*)(y + idx) = o0;
  *(f32x4*)(y + idx + 4) = o1;
}

extern "C" void kernel_launch(void* const* d_in, const int* in_sizes, int n_in,
                              void* d_out, int out_size, void* d_ws, size_t ws_size,
                              hipStream_t stream) {
  const float* x = (const float*)d_in[0];
  const float* W = (const float*)d_in[1];
  const float* b = (const float*)d_in[2];
  const int* npadd = (const int*)d_in[3];
  float* y = (float*)d_out;

  char* ws = (char*)d_ws;
  const size_t MB = 1u << 20;
  bf16* q  = (bf16*)(ws + 0 * MB);          // 8 MB  [T][C]   (dead after k_scores)
  bf16* kk = (bf16*)(ws + 8 * MB);          // 8 MB  [T][C]   (dead after k_scores)
  bf16* part0 = (bf16*)(ws + 0 * MB);       // 8 MB [T][D] bf16, overlays q
  bf16* part1 = (bf16*)(ws + 8 * MB);       // 8 MB [T][D] bf16, overlays kk
  bf16* vT = (bf16*)(ws + 16 * MB);         // 8 MB  [D][T]
  float* l = (float*)(ws + 24 * MB);        // 16 KB
  bf16* P  = (bf16*)(ws + 24 * MB + 65536); // 32 MB [T][T]
  bf16* xb = P;                              // overlap: dead before K2 writes P
  bf16* WbT = (bf16*)((char*)P + 8 * MB);    // 6 MB, also dead before K2

  // K0: convert x + transpose/convert W (merged, independent regions)
  k_prep<<<dim3(2048 + 768), 256, 0, stream>>>(x, xb, W, WbT);
  // K1: QKV projection
  k_qkv<<<dim3(N3 / 128, TT / 128), 256, 0, stream>>>(xb, WbT, b, q, kk, vT);
  // K2: masked exp-scores + row sums (compact triangular grid, XCD-chunked)
  hipMemsetAsync(l, 0, TT * sizeof(float), stream);
  k_scores<<<dim3(528), 256, 0, stream>>>(q, kk, P, l, npadd);
  // K3: 2-way split-K PV; sole-writer tiles write y directly (/l folded in)
  k_pvc<<<dim3(2, TT / 128, NFD / 128), 256, 0, stream>>>(P, vT, part0, part1, l, y, npadd);
  // K3b: finalize non-sole rows + zero pad rows
  k_norm<<<dim3((TT * NFD) / (256 * 8)), 256, 0, stream>>>(part0, part1, l, y, npadd);
}

// Round 11
// 125.114 us; speedup vs baseline: 1.1683x; 1.0269x over previous
//
#include <hip/hip_runtime.h>
#include <hip/hip_bf16.h>
#include <stdint.h>
#include <stddef.h>

#define TT 4096
#define CC 1024
#define NFD 1024
#define N3 3072
// k_pvc 4-way split-K fixed j-tile boundaries: [0,9) [9,17) [17,25) [25,32)
// -> max 8 j-tiles = 32 K-steps per block, ~600 active blocks (balanced).
#define PB0 1152   // first row using part0/part1 (it>=9)
#define PB2 2176   // first row using part2 (it>=17)

typedef __bf16 bf16;
typedef __bf16 bf16x8 __attribute__((ext_vector_type(8)));
typedef __bf16 bf16x4 __attribute__((ext_vector_type(4)));
typedef float f32x4 __attribute__((ext_vector_type(4)));

typedef const __attribute__((address_space(1))) unsigned char gl_u8;
typedef __attribute__((address_space(3))) unsigned char lds_u8;

__device__ __forceinline__ void glds16(const void* g, void* l) {
  __builtin_amdgcn_global_load_lds((gl_u8*)g, (lds_u8*)l, 16, 0, 0);
}

// Stage a 128x32 bf16 tile (row-major, ld in elements) into linear LDS [128][32].
__device__ __forceinline__ void stage128x32(const bf16* __restrict__ src, int ld, bf16* lds, int tid) {
  const int lane = tid & 63;
  const int w = tid >> 6;
#pragma unroll
  for (int p = 0; p < 2; ++p) {
    const int lbyte = w * 2048 + p * 1024;              // wave-uniform LDS base (bytes)
    const int row = (lbyte >> 6) + (lane >> 2);         // this lane's 16B lands at row, k8
    const int kel = (lane & 3) << 3;
    glds16(src + row * ld + kel, (char*)lds + lbyte);
  }
}

// ---------- R6 core (best measured): 128x128, BK=32, 2-buffer, 1 barrier/step ----------
__device__ __forceinline__ void gemm_core(const bf16* __restrict__ A, const bf16* __restrict__ B,
                                          int lda, int ldb, int ksteps,
                                          bf16* As, bf16* Bs, int tid, f32x4 (&acc)[4][4]) {
  const int lane = tid & 63;
  const int w = tid >> 6;
  const int wm = (w >> 1) * 64;
  const int wn = (w & 1) * 64;
  const int lrow = lane & 15;
  const int lko = (lane >> 4) * 8;
  stage128x32(A, lda, As, tid);
  stage128x32(B, ldb, Bs, tid);
  __syncthreads();
  for (int ks = 0; ks < ksteps; ++ks) {
    const bf16* Ac = As + (ks & 1) * 4096;
    const bf16* Bc = Bs + (ks & 1) * 4096;
    if (ks + 1 < ksteps) {
      stage128x32(A + (ks + 1) * 32, lda, As + ((ks + 1) & 1) * 4096, tid);
      stage128x32(B + (ks + 1) * 32, ldb, Bs + ((ks + 1) & 1) * 4096, tid);
    }
    bf16x8 af[4], bfr[4];
#pragma unroll
    for (int i = 0; i < 4; ++i)
      af[i] = *(const bf16x8*)(Ac + (wm + i * 16 + lrow) * 32 + lko);
#pragma unroll
    for (int i = 0; i < 4; ++i)
      bfr[i] = *(const bf16x8*)(Bc + (wn + i * 16 + lrow) * 32 + lko);
#pragma unroll
    for (int mi = 0; mi < 4; ++mi)
#pragma unroll
      for (int ni = 0; ni < 4; ++ni)
        acc[mi][ni] = __builtin_amdgcn_mfma_f32_16x16x32_bf16(af[mi], bfr[ni], acc[mi][ni], 0, 0, 0);
    __syncthreads();
  }
}

// ---- K0: merged prep. blocks [0,2048): x fp32->bf16. blocks [2048,2816): W transpose. ----
__global__ __launch_bounds__(256) void k_prep(const float* __restrict__ x, bf16* __restrict__ xb,
                                              const float* __restrict__ Wsrc, bf16* __restrict__ WbT) {
  __shared__ float Ls[64][68];
  const int tid = threadIdx.x;
  if (blockIdx.x < 2048) {
    int idx = (blockIdx.x * 256 + tid) * 8;
    f32x4 a = *(const f32x4*)(x + idx);
    f32x4 b = *(const f32x4*)(x + idx + 4);
    bf16x8 o;
#pragma unroll
    for (int j = 0; j < 4; ++j) { o[j] = (bf16)a[j]; o[4 + j] = (bf16)b[j]; }
    *(bf16x8*)(xb + idx) = o;
    return;
  }
  const int bid = blockIdx.x - 2048;
  const int n0 = (bid % 48) * 64;
  const int c0 = (bid / 48) * 64;
#pragma unroll
  for (int qq = 0; qq < 4; ++qq) {
    int lin = qq * 1024 + tid * 4;
    int r = lin >> 6, cc = lin & 63;
    f32x4 v = *(const f32x4*)(Wsrc + (size_t)(c0 + r) * N3 + n0 + cc);
#pragma unroll
    for (int j = 0; j < 4; ++j) Ls[r][cc + j] = v[j];
  }
  __syncthreads();
#pragma unroll
  for (int qq = 0; qq < 4; ++qq) {
    int lin = qq * 1024 + tid * 4;
    int nr = lin >> 6, cc = lin & 63;
    bf16x4 o;
#pragma unroll
    for (int j = 0; j < 4; ++j) o[j] = (bf16)Ls[cc + j][nr];
    *(bf16x4*)(WbT + (size_t)(n0 + nr) * CC + c0 + cc) = o;
  }
}

// ---- K1: qkv = xb @ WbT^T + b ; writes q,k natural [t][c] and v transposed [d][t] ----
__global__ __launch_bounds__(256, 2) void k_qkv(const bf16* __restrict__ xb, const bf16* __restrict__ wbt,
                                                const float* __restrict__ bias,
                                                bf16* __restrict__ q, bf16* __restrict__ k,
                                                bf16* __restrict__ vT) {
  __shared__ bf16 As[2 * 128 * 32], Bs[2 * 128 * 32];
  const int tid = threadIdx.x;
  const int m0 = blockIdx.y * 128;
  const int n0 = blockIdx.x * 128;
  f32x4 acc[4][4];
#pragma unroll
  for (int i = 0; i < 4; ++i)
#pragma unroll
    for (int j = 0; j < 4; ++j) acc[i][j] = (f32x4){0.f, 0.f, 0.f, 0.f};

  gemm_core(xb + (size_t)m0 * CC, wbt + (size_t)n0 * CC, CC, CC, CC / 32, As, Bs, tid, acc);

  const int lane = tid & 63;
  const int w = tid >> 6;
  const int wm = (w >> 1) * 64, wn = (w & 1) * 64;
  const int seg = n0 >> 10;  // 0:q 1:k 2:v
#pragma unroll
  for (int mi = 0; mi < 4; ++mi) {
    const int tB = m0 + wm + mi * 16 + ((lane >> 4) << 2);
#pragma unroll
    for (int ni = 0; ni < 4; ++ni) {
      const int n = n0 + wn + ni * 16 + (lane & 15);
      const float bb = bias[n];
      f32x4 a = acc[mi][ni];
      if (seg == 2) {
        bf16x4 pv;
#pragma unroll
        for (int r = 0; r < 4; ++r) pv[r] = (bf16)(a[r] + bb);
        *(bf16x4*)(vT + (size_t)(n - 2048) * TT + tB) = pv;  // vT[d][t]
      } else {
        bf16* dst = (seg == 0) ? q : k;
        const int nl = n & 1023;
#pragma unroll
        for (int r = 0; r < 4; ++r) dst[(size_t)(tB + r) * NFD + nl] = (bf16)(a[r] + bb);
      }
    }
  }
}

// ---- K2: P' = exp(mask(q @ k^T / 32)) as bf16; row sums l via atomicAdd.
//      1D compact triangular grid (528 blocks), band-major, XCD-chunked. ----
__global__ __launch_bounds__(256, 2) void k_scores(const bf16* __restrict__ q, const bf16* __restrict__ kk,
                                                   bf16* __restrict__ P, float* __restrict__ l,
                                                   const int* __restrict__ npadd_p) {
  const int id = blockIdx.x;
  const int lin = (id & 7) * 66 + (id >> 3);
  int band, rem;
  if (lin < 228)      { band = 0; rem = lin; }
  else if (lin < 392) { band = 1; rem = lin - 228; }
  else if (lin < 492) { band = 2; rem = lin - 392; }
  else                { band = 3; rem = lin - 492; }
  int it, jt;
  if (rem < 28) {
    int itp = (int)((sqrtf(8.0f * (float)rem + 1.0f) - 1.0f) * 0.5f);
    while ((itp + 1) * (itp + 2) / 2 <= rem) ++itp;
    while (itp * (itp + 1) / 2 > rem) --itp;
    it = band * 8 + itp;
    jt = band * 8 + (rem - itp * (itp + 1) / 2);
  } else {
    const int rem2 = rem - 28;
    it = band * 8 + 7 + (rem2 >> 3);
    jt = band * 8 + (rem2 & 7);
  }
  const int np = *npadd_p;
  const int jt0 = np >> 7;
  if (jt < jt0) return;

  __shared__ bf16 As[2 * 128 * 32], Bs[2 * 128 * 32];
  const int tid = threadIdx.x;
  f32x4 acc[4][4];
#pragma unroll
  for (int i = 0; i < 4; ++i)
#pragma unroll
    for (int j = 0; j < 4; ++j) acc[i][j] = (f32x4){0.f, 0.f, 0.f, 0.f};

  gemm_core(q + (size_t)it * 128 * CC, kk + (size_t)jt * 128 * CC, CC, CC, CC / 32, As, Bs, tid, acc);

  const int lane = tid & 63;
  const int w = tid >> 6;
  const int wm = (w >> 1) * 64, wn = (w & 1) * 64;
  const float scale = 0.03125f;  // 1/sqrt(1024)
#pragma unroll
  for (int mi = 0; mi < 4; ++mi) {
    const int iB = it * 128 + wm + mi * 16 + ((lane >> 4) << 2);
    float rs[4] = {0.f, 0.f, 0.f, 0.f};
#pragma unroll
    for (int ni = 0; ni < 4; ++ni) {
      const int j = jt * 128 + wn + ni * 16 + (lane & 15);
      f32x4 a = acc[mi][ni];
#pragma unroll
      for (int r = 0; r < 4; ++r) {
        const int i = iB + r;
        float p = 0.f;
        if (j <= i && j >= np && i >= np) p = __expf(a[r] * scale);
        const bf16 pb = (bf16)p;
        P[(size_t)i * TT + j] = pb;
        rs[r] += (float)pb;
      }
    }
#pragma unroll
    for (int r = 0; r < 4; ++r) {
      float v = rs[r];
      v += __shfl_xor(v, 1);
      v += __shfl_xor(v, 2);
      v += __shfl_xor(v, 4);
      v += __shfl_xor(v, 8);
      if ((lane & 15) == 0) atomicAdd(&l[iB + r], v);
    }
  }
}

// ---- K3a: 4-way split-K PV, no atomics. Chunk c covers j-tiles [B[c],B[c+1]) clipped
//      to the row's valid range [jt0, it+1). Sole-covering chunk writes y (*1/l).
//      Chunks 0-2 write compact bf16 partials; chunk 3 writes raw fp32 into y
//      (its rows are always finalized by k_norm). Max 32 K-steps per block. ----
__global__ __launch_bounds__(256, 2) void k_pvc(const bf16* __restrict__ P, const bf16* __restrict__ vT,
                                                bf16* __restrict__ part0, bf16* __restrict__ part1,
                                                bf16* __restrict__ part2,
                                                const float* __restrict__ l, float* __restrict__ y,
                                                const int* __restrict__ npadd_p) {
  const int c = blockIdx.x;       // 0..3
  const int it = blockIdx.y;      // 0..31
  const int d0 = blockIdx.z * 128;
  const int np = *npadd_p;
  const int jt0 = np >> 7;
  const int lo = (c == 0) ? 0 : (c == 1 ? 9 : (c == 2 ? 17 : 25));
  const int hi = (c == 0) ? 9 : (c == 1 ? 17 : (c == 2 ? 25 : 32));
  const int jlo = max(lo, jt0);
  const int jhi = min(hi, it + 1);
  if (jlo >= jhi) return;

  __shared__ bf16 As[2 * 128 * 32], Bs[2 * 128 * 32];
  const int tid = threadIdx.x;
  f32x4 acc[4][4];
#pragma unroll
  for (int i = 0; i < 4; ++i)
#pragma unroll
    for (int j = 0; j < 4; ++j) acc[i][j] = (f32x4){0.f, 0.f, 0.f, 0.f};

  gemm_core(P + (size_t)it * 128 * TT + (size_t)jlo * 128,
            vT + (size_t)d0 * TT + (size_t)jlo * 128,
            TT, TT, (jhi - jlo) * 4, As, Bs, tid, acc);

  const int lane = tid & 63;
  const int w = tid >> 6;
  const int wm = (w >> 1) * 64, wn = (w & 1) * 64;
  const bool sole = (jlo == jt0) && (jhi == it + 1);  // covers the row's entire valid range
  if (sole) {
#pragma unroll
    for (int mi = 0; mi < 4; ++mi) {
      const int iB = it * 128 + wm + mi * 16 + ((lane >> 4) << 2);
      float inv4[4];
#pragma unroll
      for (int r = 0; r < 4; ++r) {
        const int i = iB + r;
        inv4[r] = (i >= np) ? (1.0f / l[i]) : 0.0f;
      }
#pragma unroll
      for (int ni = 0; ni < 4; ++ni) {
        const int d = d0 + wn + ni * 16 + (lane & 15);
        f32x4 a = acc[mi][ni];
#pragma unroll
        for (int r = 0; r < 4; ++r)
          y[(size_t)(iB + r) * NFD + d] = a[r] * inv4[r];
      }
    }
  } else if (c == 3) {
    // raw fp32 partial into y; k_norm finalizes these rows (it>=25 here)
#pragma unroll
    for (int mi = 0; mi < 4; ++mi) {
      const int iB = it * 128 + wm + mi * 16 + ((lane >> 4) << 2);
#pragma unroll
      for (int ni = 0; ni < 4; ++ni) {
        const int d = d0 + wn + ni * 16 + (lane & 15);
        f32x4 a = acc[mi][ni];
#pragma unroll
        for (int r = 0; r < 4; ++r)
          y[(size_t)(iB + r) * NFD + d] = a[r];
      }
    }
  } else {
    bf16* __restrict__ part = (c == 0) ? part0 : (c == 1 ? part1 : part2);
    const int base = (c == 2) ? (PB2 * NFD) : (PB0 * NFD);  // compact buffers
#pragma unroll
    for (int mi = 0; mi < 4; ++mi) {
      const int iB = it * 128 + wm + mi * 16 + ((lane >> 4) << 2);
#pragma unroll
      for (int ni = 0; ni < 4; ++ni) {
        const int d = d0 + wn + ni * 16 + (lane & 15);
        f32x4 a = acc[mi][ni];
#pragma unroll
        for (int r = 0; r < 4; ++r)
          part[(size_t)(iB + r) * NFD + d - base] = (bf16)a[r];
      }
    }
  }
}

// ---- K3b: finalize multi-chunk rows: y = (sum of active partials [+ y fp32]) / l.
//      Pad rows (i<np): zero. Single-chunk rows: y already final -> exit. ----
__global__ __launch_bounds__(256) void k_norm(const bf16* __restrict__ part0, const bf16* __restrict__ part1,
                                              const bf16* __restrict__ part2,
                                              const float* __restrict__ l, float* __restrict__ y,
                                              const int* __restrict__ npadd_p) {
  const int idx = (blockIdx.x * 256 + threadIdx.x) * 8;
  const int i = idx >> 10;  // / NFD
  const int np = *npadd_p;
  if (i < np) {
    f32x4 z = (f32x4){0.f, 0.f, 0.f, 0.f};
    *(f32x4*)(y + idx) = z;
    *(f32x4*)(y + idx + 4) = z;
    return;
  }
  const int jt0 = np >> 7;
  const int it = i >> 7;
  const int ip1 = it + 1;
  const bool a0 = (max(0, jt0)  < min(9, ip1));
  const bool a1 = (max(9, jt0)  < min(17, ip1));
  const bool a2 = (max(17, jt0) < min(25, ip1));
  const bool a3 = (max(25, jt0) < min(32, ip1));
  const int cnt = (int)a0 + (int)a1 + (int)a2 + (int)a3;
  if (cnt <= 1) return;  // sole-writer row: y already final
  float s[8] = {0.f, 0.f, 0.f, 0.f, 0.f, 0.f, 0.f, 0.f};
  if (a0) {  // row has it>=9 here (cnt>=2)
    bf16x8 a = *(const bf16x8*)(part0 + idx - PB0 * NFD);
#pragma unroll
    for (int j = 0; j < 8; ++j) s[j] += (float)a[j];
  }
  if (a1) {
    bf16x8 a = *(const bf16x8*)(part1 + idx - PB0 * NFD);
#pragma unroll
    for (int j = 0; j < 8; ++j) s[j] += (float)a[j];
  }
  if (a2) {  // it>=17
    bf16x8 a = *(const bf16x8*)(part2 + idx - PB2 * NFD);
#pragma unroll
    for (int j = 0; j < 8; ++j) s[j] += (float)a[j];
  }
  if (a3) {  // chunk3's raw fp32 partial lives in y
    f32x4 a = *(const f32x4*)(y + idx);
    f32x4 b = *(const f32x4*)(y + idx + 4);
#pragma unroll
    for (int j = 0; j < 4; ++j) { s[j] += a[j]; s[4 + j] += b[j]; }
  }
  const float inv = 1.0f / l[i];
  f32x4 o0, o1;
#pragma unroll
  for (int j = 0; j < 4; ++j) { o0[j] = s[j] * inv; o1[j] = s[4 + j] * inv; }
  *(f32x4*)(y + idx) = o0;
  *(f32x4*)(y + idx + 4) = o1;
}

extern "C" void kernel_launch(void* const* d_in, const int* in_sizes, int n_in,
                              void* d_out, int out_size, void* d_ws, size_t ws_size,
                              hipStream_t stream) {
  const float* x = (const float*)d_in[0];
  const float* W = (const float*)d_in[1];
  const float* b = (const float*)d_in[2];
  const int* npadd = (const int*)d_in[3];
  float* y = (float*)d_out;

  char* ws = (char*)d_ws;
  const size_t MB = 1u << 20;
  bf16* q  = (bf16*)(ws + 0 * MB);          // 8 MB  [T][C]   (dead after k_scores)
  bf16* kk = (bf16*)(ws + 8 * MB);          // 8 MB  [T][C]   (dead after k_scores)
  // compact PV partials overlay q/kk (15.25 MB total <= 16 MB):
  bf16* part0 = (bf16*)(ws + 0 * MB);                        // rows [1152,4096): 5.75 MB
  bf16* part1 = (bf16*)(ws + (size_t)(TT - PB0) * NFD * 2);  // rows [1152,4096): 5.75 MB
  bf16* part2 = (bf16*)(ws + (size_t)2 * (TT - PB0) * NFD * 2);  // rows [2176,4096): 3.75 MB
  bf16* vT = (bf16*)(ws + 16 * MB);         // 8 MB  [D][T]
  float* l = (float*)(ws + 24 * MB);        // 16 KB
  bf16* P  = (bf16*)(ws + 24 * MB + 65536); // 32 MB [T][T]
  bf16* xb = P;                              // overlap: dead before K2 writes P
  bf16* WbT = (bf16*)((char*)P + 8 * MB);    // 6 MB, also dead before K2

  // K0: convert x + transpose/convert W (merged, independent regions)
  k_prep<<<dim3(2048 + 768), 256, 0, stream>>>(x, xb, W, WbT);
  // K1: QKV projection
  k_qkv<<<dim3(N3 / 128, TT / 128), 256, 0, stream>>>(xb, WbT, b, q, kk, vT);
  // K2: masked exp-scores + row sums (compact triangular grid, XCD-chunked)
  hipMemsetAsync(l, 0, TT * sizeof(float), stream);
  k_scores<<<dim3(528), 256, 0, stream>>>(q, kk, P, l, npadd);
  // K3: 4-way split-K PV (balanced <=32 K-steps; sole tiles write y with /l folded)
  k_pvc<<<dim3(4, TT / 128, NFD / 128), 256, 0, stream>>>(P, vT, part0, part1, part2, l, y, npadd);
  // K3b: finalize multi-chunk rows + zero pad rows
  k_norm<<<dim3((TT * NFD) / (256 * 8)), 256, 0, stream>>>(part0, part1, part2, l, y, npadd);
}

// Round 12
// 120.312 us; speedup vs baseline: 1.2149x; 1.0399x over previous
//
#include <hip/hip_runtime.h>
#include <hip/hip_bf16.h>
#include <stdint.h>
#include <stddef.h>

#define TT 4096
#define CC 1024
#define NFD 1024
#define N3 3072
// k_pvc 4-way split-K fixed j-tile boundaries: [0,9) [9,17) [17,25) [25,32)
#define PB0 1152   // first row using part0/part1 (it>=9)
#define PB2 2176   // first row using part2 (it>=17)

typedef __bf16 bf16;
typedef __bf16 bf16x8 __attribute__((ext_vector_type(8)));
typedef __bf16 bf16x4 __attribute__((ext_vector_type(4)));
typedef float f32x4 __attribute__((ext_vector_type(4)));

typedef const __attribute__((address_space(1))) unsigned char gl_u8;
typedef __attribute__((address_space(3))) unsigned char lds_u8;

__device__ __forceinline__ void glds16(const void* g, void* l) {
  __builtin_amdgcn_global_load_lds((gl_u8*)g, (lds_u8*)l, 16, 0, 0);
}

// Stage a 128x32 bf16 tile (row-major, ld in elements) into linear LDS [128][32].
__device__ __forceinline__ void stage128x32(const bf16* __restrict__ src, int ld, bf16* lds, int tid) {
  const int lane = tid & 63;
  const int w = tid >> 6;
#pragma unroll
  for (int p = 0; p < 2; ++p) {
    const int lbyte = w * 2048 + p * 1024;              // wave-uniform LDS base (bytes)
    const int row = (lbyte >> 6) + (lane >> 2);         // this lane's 16B lands at row, k8
    const int kel = (lane & 3) << 3;
    glds16(src + row * ld + kel, (char*)lds + lbyte);
  }
}

// ---------- R6 core (best measured): 128x128, BK=32, 2-buffer, 1 barrier/step ----------
__device__ __forceinline__ void gemm_core(const bf16* __restrict__ A, const bf16* __restrict__ B,
                                          int lda, int ldb, int ksteps,
                                          bf16* As, bf16* Bs, int tid, f32x4 (&acc)[4][4]) {
  const int lane = tid & 63;
  const int w = tid >> 6;
  const int wm = (w >> 1) * 64;
  const int wn = (w & 1) * 64;
  const int lrow = lane & 15;
  const int lko = (lane >> 4) * 8;
  stage128x32(A, lda, As, tid);
  stage128x32(B, ldb, Bs, tid);
  __syncthreads();
  for (int ks = 0; ks < ksteps; ++ks) {
    const bf16* Ac = As + (ks & 1) * 4096;
    const bf16* Bc = Bs + (ks & 1) * 4096;
    if (ks + 1 < ksteps) {
      stage128x32(A + (ks + 1) * 32, lda, As + ((ks + 1) & 1) * 4096, tid);
      stage128x32(B + (ks + 1) * 32, ldb, Bs + ((ks + 1) & 1) * 4096, tid);
    }
    bf16x8 af[4], bfr[4];
#pragma unroll
    for (int i = 0; i < 4; ++i)
      af[i] = *(const bf16x8*)(Ac + (wm + i * 16 + lrow) * 32 + lko);
#pragma unroll
    for (int i = 0; i < 4; ++i)
      bfr[i] = *(const bf16x8*)(Bc + (wn + i * 16 + lrow) * 32 + lko);
#pragma unroll
    for (int mi = 0; mi < 4; ++mi)
#pragma unroll
      for (int ni = 0; ni < 4; ++ni)
        acc[mi][ni] = __builtin_amdgcn_mfma_f32_16x16x32_bf16(af[mi], bfr[ni], acc[mi][ni], 0, 0, 0);
    __syncthreads();
  }
}

// ---- K0: merged prep. [0,2048): x cvt. [2048,2816): W transpose. 2816: zero l. ----
__global__ __launch_bounds__(256) void k_prep(const float* __restrict__ x, bf16* __restrict__ xb,
                                              const float* __restrict__ Wsrc, bf16* __restrict__ WbT,
                                              float* __restrict__ l) {
  __shared__ float Ls[64][68];
  const int tid = threadIdx.x;
  if (blockIdx.x < 2048) {
    int idx = (blockIdx.x * 256 + tid) * 8;
    f32x4 a = *(const f32x4*)(x + idx);
    f32x4 b = *(const f32x4*)(x + idx + 4);
    bf16x8 o;
#pragma unroll
    for (int j = 0; j < 4; ++j) { o[j] = (bf16)a[j]; o[4 + j] = (bf16)b[j]; }
    *(bf16x8*)(xb + idx) = o;
    return;
  }
  if (blockIdx.x == 2048 + 768) {  // zero the l accumulator (TT floats)
    f32x4 z = (f32x4){0.f, 0.f, 0.f, 0.f};
#pragma unroll
    for (int qq = 0; qq < 4; ++qq)
      *(f32x4*)(l + (qq * 256 + tid) * 4) = z;
    return;
  }
  const int bid = blockIdx.x - 2048;
  const int n0 = (bid % 48) * 64;
  const int c0 = (bid / 48) * 64;
#pragma unroll
  for (int qq = 0; qq < 4; ++qq) {
    int lin = qq * 1024 + tid * 4;
    int r = lin >> 6, cc = lin & 63;
    f32x4 v = *(const f32x4*)(Wsrc + (size_t)(c0 + r) * N3 + n0 + cc);
#pragma unroll
    for (int j = 0; j < 4; ++j) Ls[r][cc + j] = v[j];
  }
  __syncthreads();
#pragma unroll
  for (int qq = 0; qq < 4; ++qq) {
    int lin = qq * 1024 + tid * 4;
    int nr = lin >> 6, cc = lin & 63;
    bf16x4 o;
#pragma unroll
    for (int j = 0; j < 4; ++j) o[j] = (bf16)Ls[cc + j][nr];
    *(bf16x4*)(WbT + (size_t)(n0 + nr) * CC + c0 + cc) = o;
  }
}

// ---- K1: qkv = xb @ WbT^T + b ; writes q,k natural [t][c] and v transposed [d][t] ----
__global__ __launch_bounds__(256, 2) void k_qkv(const bf16* __restrict__ xb, const bf16* __restrict__ wbt,
                                                const float* __restrict__ bias,
                                                bf16* __restrict__ q, bf16* __restrict__ k,
                                                bf16* __restrict__ vT) {
  __shared__ bf16 As[2 * 128 * 32], Bs[2 * 128 * 32];
  const int tid = threadIdx.x;
  const int m0 = blockIdx.y * 128;
  const int n0 = blockIdx.x * 128;
  f32x4 acc[4][4];
#pragma unroll
  for (int i = 0; i < 4; ++i)
#pragma unroll
    for (int j = 0; j < 4; ++j) acc[i][j] = (f32x4){0.f, 0.f, 0.f, 0.f};

  gemm_core(xb + (size_t)m0 * CC, wbt + (size_t)n0 * CC, CC, CC, CC / 32, As, Bs, tid, acc);

  const int lane = tid & 63;
  const int w = tid >> 6;
  const int wm = (w >> 1) * 64, wn = (w & 1) * 64;
  const int seg = n0 >> 10;  // 0:q 1:k 2:v
#pragma unroll
  for (int mi = 0; mi < 4; ++mi) {
    const int tB = m0 + wm + mi * 16 + ((lane >> 4) << 2);
#pragma unroll
    for (int ni = 0; ni < 4; ++ni) {
      const int n = n0 + wn + ni * 16 + (lane & 15);
      const float bb = bias[n];
      f32x4 a = acc[mi][ni];
      if (seg == 2) {
        bf16x4 pv;
#pragma unroll
        for (int r = 0; r < 4; ++r) pv[r] = (bf16)(a[r] + bb);
        *(bf16x4*)(vT + (size_t)(n - 2048) * TT + tB) = pv;  // vT[d][t]
      } else {
        bf16* dst = (seg == 0) ? q : k;
        const int nl = n & 1023;
#pragma unroll
        for (int r = 0; r < 4; ++r) dst[(size_t)(tB + r) * NFD + nl] = (bf16)(a[r] + bb);
      }
    }
  }
}

// ---- K2: P' = exp(mask(q @ k^T / 32)) as bf16; row sums l via atomicAdd.
//      1D compact triangular grid (528 blocks), band-major, XCD-chunked. ----
__global__ __launch_bounds__(256, 2) void k_scores(const bf16* __restrict__ q, const bf16* __restrict__ kk,
                                                   bf16* __restrict__ P, float* __restrict__ l,
                                                   const int* __restrict__ npadd_p) {
  const int id = blockIdx.x;
  const int lin = (id & 7) * 66 + (id >> 3);
  int band, rem;
  if (lin < 228)      { band = 0; rem = lin; }
  else if (lin < 392) { band = 1; rem = lin - 228; }
  else if (lin < 492) { band = 2; rem = lin - 392; }
  else                { band = 3; rem = lin - 492; }
  int it, jt;
  if (rem < 28) {
    int itp = (int)((sqrtf(8.0f * (float)rem + 1.0f) - 1.0f) * 0.5f);
    while ((itp + 1) * (itp + 2) / 2 <= rem) ++itp;
    while (itp * (itp + 1) / 2 > rem) --itp;
    it = band * 8 + itp;
    jt = band * 8 + (rem - itp * (itp + 1) / 2);
  } else {
    const int rem2 = rem - 28;
    it = band * 8 + 7 + (rem2 >> 3);
    jt = band * 8 + (rem2 & 7);
  }
  const int np = *npadd_p;
  const int jt0 = np >> 7;
  if (jt < jt0) return;

  __shared__ bf16 As[2 * 128 * 32], Bs[2 * 128 * 32];
  const int tid = threadIdx.x;
  f32x4 acc[4][4];
#pragma unroll
  for (int i = 0; i < 4; ++i)
#pragma unroll
    for (int j = 0; j < 4; ++j) acc[i][j] = (f32x4){0.f, 0.f, 0.f, 0.f};

  gemm_core(q + (size_t)it * 128 * CC, kk + (size_t)jt * 128 * CC, CC, CC, CC / 32, As, Bs, tid, acc);

  const int lane = tid & 63;
  const int w = tid >> 6;
  const int wm = (w >> 1) * 64, wn = (w & 1) * 64;
  const float scale = 0.03125f;  // 1/sqrt(1024)
#pragma unroll
  for (int mi = 0; mi < 4; ++mi) {
    const int iB = it * 128 + wm + mi * 16 + ((lane >> 4) << 2);
    float rs[4] = {0.f, 0.f, 0.f, 0.f};
#pragma unroll
    for (int ni = 0; ni < 4; ++ni) {
      const int j = jt * 128 + wn + ni * 16 + (lane & 15);
      f32x4 a = acc[mi][ni];
#pragma unroll
      for (int r = 0; r < 4; ++r) {
        const int i = iB + r;
        float p = 0.f;
        if (j <= i && j >= np && i >= np) p = __expf(a[r] * scale);
        const bf16 pb = (bf16)p;
        P[(size_t)i * TT + j] = pb;
        rs[r] += (float)pb;
      }
    }
#pragma unroll
    for (int r = 0; r < 4; ++r) {
      float v = rs[r];
      v += __shfl_xor(v, 1);
      v += __shfl_xor(v, 2);
      v += __shfl_xor(v, 4);
      v += __shfl_xor(v, 8);
      if ((lane & 15) == 0) atomicAdd(&l[iB + r], v);
    }
  }
}

// ---- K3a: 4-way split-K PV, no atomics, XCD sibling co-location.
//      1D grid of 1024; decode so the 8 d0-blocks of one (it,chunk) pair share
//      id%8 (same XCD) and sit within a 64-id dispatch window -> the 256 KB
//      P-stripe is fetched to that XCD's L2 once and hit by the other 7. ----
__global__ __launch_bounds__(256, 2) void k_pvc(const bf16* __restrict__ P, const bf16* __restrict__ vT,
                                                bf16* __restrict__ part0, bf16* __restrict__ part1,
                                                bf16* __restrict__ part2,
                                                const float* __restrict__ l, float* __restrict__ y,
                                                const int* __restrict__ npadd_p) {
  const int id = blockIdx.x;          // 0..1023
  const int kgrp = id >> 3;           // 0..127
  const int d0 = (kgrp & 7) * 128;    // d0 index varies within the sibling window
  const int p = (id & 7) + 8 * (kgrp >> 3);  // pair 0..127, id%8 == p%8 -> same XCD
  const int it = p >> 2;              // 0..31
  const int c = p & 3;                // 0..3
  const int np = *npadd_p;
  const int jt0 = np >> 7;
  const int lo = (c == 0) ? 0 : (c == 1 ? 9 : (c == 2 ? 17 : 25));
  const int hi = (c == 0) ? 9 : (c == 1 ? 17 : (c == 2 ? 25 : 32));
  const int jlo = max(lo, jt0);
  const int jhi = min(hi, it + 1);
  if (jlo >= jhi) return;

  __shared__ bf16 As[2 * 128 * 32], Bs[2 * 128 * 32];
  const int tid = threadIdx.x;
  f32x4 acc[4][4];
#pragma unroll
  for (int i = 0; i < 4; ++i)
#pragma unroll
    for (int j = 0; j < 4; ++j) acc[i][j] = (f32x4){0.f, 0.f, 0.f, 0.f};

  gemm_core(P + (size_t)it * 128 * TT + (size_t)jlo * 128,
            vT + (size_t)d0 * TT + (size_t)jlo * 128,
            TT, TT, (jhi - jlo) * 4, As, Bs, tid, acc);

  const int lane = tid & 63;
  const int w = tid >> 6;
  const int wm = (w >> 1) * 64, wn = (w & 1) * 64;
  const bool sole = (jlo == jt0) && (jhi == it + 1);
  if (sole) {
#pragma unroll
    for (int mi = 0; mi < 4; ++mi) {
      const int iB = it * 128 + wm + mi * 16 + ((lane >> 4) << 2);
      float inv4[4];
#pragma unroll
      for (int r = 0; r < 4; ++r) {
        const int i = iB + r;
        inv4[r] = (i >= np) ? (1.0f / l[i]) : 0.0f;
      }
#pragma unroll
      for (int ni = 0; ni < 4; ++ni) {
        const int d = d0 + wn + ni * 16 + (lane & 15);
        f32x4 a = acc[mi][ni];
#pragma unroll
        for (int r = 0; r < 4; ++r)
          y[(size_t)(iB + r) * NFD + d] = a[r] * inv4[r];
      }
    }
  } else if (c == 3) {
    // raw fp32 partial into y; k_norm finalizes these rows (it>=25 here)
#pragma unroll
    for (int mi = 0; mi < 4; ++mi) {
      const int iB = it * 128 + wm + mi * 16 + ((lane >> 4) << 2);
#pragma unroll
      for (int ni = 0; ni < 4; ++ni) {
        const int d = d0 + wn + ni * 16 + (lane & 15);
        f32x4 a = acc[mi][ni];
#pragma unroll
        for (int r = 0; r < 4; ++r)
          y[(size_t)(iB + r) * NFD + d] = a[r];
      }
    }
  } else {
    bf16* __restrict__ part = (c == 0) ? part0 : (c == 1 ? part1 : part2);
    const int base = (c == 2) ? (PB2 * NFD) : (PB0 * NFD);
#pragma unroll
    for (int mi = 0; mi < 4; ++mi) {
      const int iB = it * 128 + wm + mi * 16 + ((lane >> 4) << 2);
#pragma unroll
      for (int ni = 0; ni < 4; ++ni) {
        const int d = d0 + wn + ni * 16 + (lane & 15);
        f32x4 a = acc[mi][ni];
#pragma unroll
        for (int r = 0; r < 4; ++r)
          part[(size_t)(iB + r) * NFD + d - base] = (bf16)a[r];
      }
    }
  }
}

// ---- K3b: finalize multi-chunk rows: y = (sum of active partials [+ y fp32]) / l. ----
__global__ __launch_bounds__(256) void k_norm(const bf16* __restrict__ part0, const bf16* __restrict__ part1,
                                              const bf16* __restrict__ part2,
                                              const float* __restrict__ l, float* __restrict__ y,
                                              const int* __restrict__ npadd_p) {
  const int idx = (blockIdx.x * 256 + threadIdx.x) * 8;
  const int i = idx >> 10;  // / NFD
  const int np = *npadd_p;
  if (i < np) {
    f32x4 z = (f32x4){0.f, 0.f, 0.f, 0.f};
    *(f32x4*)(y + idx) = z;
    *(f32x4*)(y + idx + 4) = z;
    return;
  }
  const int jt0 = np >> 7;
  const int it = i >> 7;
  const int ip1 = it + 1;
  const bool a0 = (max(0, jt0)  < min(9, ip1));
  const bool a1 = (max(9, jt0)  < min(17, ip1));
  const bool a2 = (max(17, jt0) < min(25, ip1));
  const bool a3 = (max(25, jt0) < min(32, ip1));
  const int cnt = (int)a0 + (int)a1 + (int)a2 + (int)a3;
  if (cnt <= 1) return;  // sole-writer row: y already final
  float s[8] = {0.f, 0.f, 0.f, 0.f, 0.f, 0.f, 0.f, 0.f};
  if (a0) {
    bf16x8 a = *(const bf16x8*)(part0 + idx - PB0 * NFD);
#pragma unroll
    for (int j = 0; j < 8; ++j) s[j] += (float)a[j];
  }
  if (a1) {
    bf16x8 a = *(const bf16x8*)(part1 + idx - PB0 * NFD);
#pragma unroll
    for (int j = 0; j < 8; ++j) s[j] += (float)a[j];
  }
  if (a2) {
    bf16x8 a = *(const bf16x8*)(part2 + idx - PB2 * NFD);
#pragma unroll
    for (int j = 0; j < 8; ++j) s[j] += (float)a[j];
  }
  if (a3) {
    f32x4 a = *(const f32x4*)(y + idx);
    f32x4 b = *(const f32x4*)(y + idx + 4);
#pragma unroll
    for (int j = 0; j < 4; ++j) { s[j] += a[j]; s[4 + j] += b[j]; }
  }
  const float inv = 1.0f / l[i];
  f32x4 o0, o1;
#pragma unroll
  for (int j = 0; j < 4; ++j) { o0[j] = s[j] * inv; o1[j] = s[4 + j] * inv; }
  *(f32x4*)(y + idx) = o0;
  *(f32x4*)(y + idx + 4) = o1;
}

extern "C" void kernel_launch(void* const* d_in, const int* in_sizes, int n_in,
                              void* d_out, int out_size, void* d_ws, size_t ws_size,
                              hipStream_t stream) {
  const float* x = (const float*)d_in[0];
  const float* W = (const float*)d_in[1];
  const float* b = (const float*)d_in[2];
  const int* npadd = (const int*)d_in[3];
  float* y = (float*)d_out;

  char* ws = (char*)d_ws;
  const size_t MB = 1u << 20;
  bf16* q  = (bf16*)(ws + 0 * MB);          // 8 MB  [T][C]   (dead after k_scores)
  bf16* kk = (bf16*)(ws + 8 * MB);          // 8 MB  [T][C]   (dead after k_scores)
  // compact PV partials overlay q/kk (15.25 MB total <= 16 MB):
  bf16* part0 = (bf16*)(ws + 0 * MB);                        // rows [1152,4096)
  bf16* part1 = (bf16*)(ws + (size_t)(TT - PB0) * NFD * 2);  // rows [1152,4096)
  bf16* part2 = (bf16*)(ws + (size_t)2 * (TT - PB0) * NFD * 2);  // rows [2176,4096)
  bf16* vT = (bf16*)(ws + 16 * MB);         // 8 MB  [D][T]
  float* l = (float*)(ws + 24 * MB);        // 16 KB
  bf16* P  = (bf16*)(ws + 24 * MB + 65536); // 32 MB [T][T]
  bf16* xb = P;                              // overlap: dead before K2 writes P
  bf16* WbT = (bf16*)((char*)P + 8 * MB);    // 6 MB, also dead before K2

  // K0: convert x + transpose/convert W + zero l (merged)
  k_prep<<<dim3(2048 + 768 + 1), 256, 0, stream>>>(x, xb, W, WbT, l);
  // K1: QKV projection
  k_qkv<<<dim3(N3 / 128, TT / 128), 256, 0, stream>>>(xb, WbT, b, q, kk, vT);
  // K2: masked exp-scores + row sums (compact triangular grid, XCD-chunked)
  k_scores<<<dim3(528), 256, 0, stream>>>(q, kk, P, l, npadd);
  // K3: 4-way split-K PV, XCD sibling co-location for P-stripe L2 reuse
  k_pvc<<<dim3(1024), 256, 0, stream>>>(P, vT, part0, part1, part2, l, y, npadd);
  // K3b: finalize multi-chunk rows + zero pad rows
  k_norm<<<dim3((TT * NFD) / (256 * 8)), 256, 0, stream>>>(part0, part1, part2, l, y, npadd);
}

// Round 13
// 118.221 us; speedup vs baseline: 1.2364x; 1.0177x over previous
//
#include <hip/hip_runtime.h>
#include <hip/hip_bf16.h>
#include <stdint.h>
#include <stddef.h>

#define TT 4096
#define CC 1024
#define NFD 1024
#define N3 3072
// k_pvc 4-way split-K fixed j-tile boundaries: [0,9) [9,17) [17,25) [25,32)
#define PB0 1152   // first row using part0/part1 (it>=9)
#define PB2 2176   // first row using part2 (it>=17)

typedef __bf16 bf16;
typedef __bf16 bf16x8 __attribute__((ext_vector_type(8)));
typedef __bf16 bf16x4 __attribute__((ext_vector_type(4)));
typedef float f32x4 __attribute__((ext_vector_type(4)));

typedef const __attribute__((address_space(1))) unsigned char gl_u8;
typedef __attribute__((address_space(3))) unsigned char lds_u8;

__device__ __forceinline__ void glds16(const void* g, void* l) {
  __builtin_amdgcn_global_load_lds((gl_u8*)g, (lds_u8*)l, 16, 0, 0);
}

// Stage a 128x32 bf16 tile (row-major, ld in elements) into linear LDS [128][32].
__device__ __forceinline__ void stage128x32(const bf16* __restrict__ src, int ld, bf16* lds, int tid) {
  const int lane = tid & 63;
  const int w = tid >> 6;
#pragma unroll
  for (int p = 0; p < 2; ++p) {
    const int lbyte = w * 2048 + p * 1024;              // wave-uniform LDS base (bytes)
    const int row = (lbyte >> 6) + (lane >> 2);         // this lane's 16B lands at row, k8
    const int kel = (lane & 3) << 3;
    glds16(src + row * ld + kel, (char*)lds + lbyte);
  }
}

// ---------- R6 core (best measured): 128x128, BK=32, 2-buffer, 1 barrier/step ----------
__device__ __forceinline__ void gemm_core(const bf16* __restrict__ A, const bf16* __restrict__ B,
                                          int lda, int ldb, int ksteps,
                                          bf16* As, bf16* Bs, int tid, f32x4 (&acc)[4][4]) {
  const int lane = tid & 63;
  const int w = tid >> 6;
  const int wm = (w >> 1) * 64;
  const int wn = (w & 1) * 64;
  const int lrow = lane & 15;
  const int lko = (lane >> 4) * 8;
  stage128x32(A, lda, As, tid);
  stage128x32(B, ldb, Bs, tid);
  __syncthreads();
  for (int ks = 0; ks < ksteps; ++ks) {
    const bf16* Ac = As + (ks & 1) * 4096;
    const bf16* Bc = Bs + (ks & 1) * 4096;
    if (ks + 1 < ksteps) {
      stage128x32(A + (ks + 1) * 32, lda, As + ((ks + 1) & 1) * 4096, tid);
      stage128x32(B + (ks + 1) * 32, ldb, Bs + ((ks + 1) & 1) * 4096, tid);
    }
    bf16x8 af[4], bfr[4];
#pragma unroll
    for (int i = 0; i < 4; ++i)
      af[i] = *(const bf16x8*)(Ac + (wm + i * 16 + lrow) * 32 + lko);
#pragma unroll
    for (int i = 0; i < 4; ++i)
      bfr[i] = *(const bf16x8*)(Bc + (wn + i * 16 + lrow) * 32 + lko);
#pragma unroll
    for (int mi = 0; mi < 4; ++mi)
#pragma unroll
      for (int ni = 0; ni < 4; ++ni)
        acc[mi][ni] = __builtin_amdgcn_mfma_f32_16x16x32_bf16(af[mi], bfr[ni], acc[mi][ni], 0, 0, 0);
    __syncthreads();
  }
}

// ---- K0: merged prep. [0,2048): x cvt. [2048,2816): W transpose. 2816: zero l. ----
__global__ __launch_bounds__(256) void k_prep(const float* __restrict__ x, bf16* __restrict__ xb,
                                              const float* __restrict__ Wsrc, bf16* __restrict__ WbT,
                                              float* __restrict__ l) {
  __shared__ float Ls[64][68];
  const int tid = threadIdx.x;
  if (blockIdx.x < 2048) {
    int idx = (blockIdx.x * 256 + tid) * 8;
    f32x4 a = *(const f32x4*)(x + idx);
    f32x4 b = *(const f32x4*)(x + idx + 4);
    bf16x8 o;
#pragma unroll
    for (int j = 0; j < 4; ++j) { o[j] = (bf16)a[j]; o[4 + j] = (bf16)b[j]; }
    *(bf16x8*)(xb + idx) = o;
    return;
  }
  if (blockIdx.x == 2048 + 768) {  // zero the l accumulator (TT floats)
    f32x4 z = (f32x4){0.f, 0.f, 0.f, 0.f};
#pragma unroll
    for (int qq = 0; qq < 4; ++qq)
      *(f32x4*)(l + (qq * 256 + tid) * 4) = z;
    return;
  }
  const int bid = blockIdx.x - 2048;
  const int n0 = (bid % 48) * 64;
  const int c0 = (bid / 48) * 64;
#pragma unroll
  for (int qq = 0; qq < 4; ++qq) {
    int lin = qq * 1024 + tid * 4;
    int r = lin >> 6, cc = lin & 63;
    f32x4 v = *(const f32x4*)(Wsrc + (size_t)(c0 + r) * N3 + n0 + cc);
#pragma unroll
    for (int j = 0; j < 4; ++j) Ls[r][cc + j] = v[j];
  }
  __syncthreads();
#pragma unroll
  for (int qq = 0; qq < 4; ++qq) {
    int lin = qq * 1024 + tid * 4;
    int nr = lin >> 6, cc = lin & 63;
    bf16x4 o;
#pragma unroll
    for (int j = 0; j < 4; ++j) o[j] = (bf16)Ls[cc + j][nr];
    *(bf16x4*)(WbT + (size_t)(n0 + nr) * CC + c0 + cc) = o;
  }
}

// ---- K1: qkv = xb @ WbT^T + b. 1D XCD-chunked grid: XCD r (id&7) owns it-rows
//      [4r,4r+4) x all 24 jt = its exactly-resident 96 blocks -> per-K-step slice
//      working set = 4 A-slices (24-way shared) + 24 B-slices (4-way shared),
//      each fetched once per XCD and L2-hit by sharers. ----
__global__ __launch_bounds__(256, 2) void k_qkv(const bf16* __restrict__ xb, const bf16* __restrict__ wbt,
                                                const float* __restrict__ bias,
                                                bf16* __restrict__ q, bf16* __restrict__ k,
                                                bf16* __restrict__ vT) {
  __shared__ bf16 As[2 * 128 * 32], Bs[2 * 128 * 32];
  const int tid = threadIdx.x;
  const int id = blockIdx.x;         // 0..767
  const int r = id & 7;              // XCD (round-robin heuristic, m09)
  const int s = id >> 3;             // 0..95 within XCD
  const int it = 4 * r + (s & 3);    // 0..31
  const int jt = s >> 2;             // 0..23
  const int m0 = it * 128;
  const int n0 = jt * 128;
  f32x4 acc[4][4];
#pragma unroll
  for (int i = 0; i < 4; ++i)
#pragma unroll
    for (int j = 0; j < 4; ++j) acc[i][j] = (f32x4){0.f, 0.f, 0.f, 0.f};

  gemm_core(xb + (size_t)m0 * CC, wbt + (size_t)n0 * CC, CC, CC, CC / 32, As, Bs, tid, acc);

  const int lane = tid & 63;
  const int w = tid >> 6;
  const int wm = (w >> 1) * 64, wn = (w & 1) * 64;
  const int seg = n0 >> 10;  // 0:q 1:k 2:v
#pragma unroll
  for (int mi = 0; mi < 4; ++mi) {
    const int tB = m0 + wm + mi * 16 + ((lane >> 4) << 2);
#pragma unroll
    for (int ni = 0; ni < 4; ++ni) {
      const int n = n0 + wn + ni * 16 + (lane & 15);
      const float bb = bias[n];
      f32x4 a = acc[mi][ni];
      if (seg == 2) {
        bf16x4 pv;
#pragma unroll
        for (int r2 = 0; r2 < 4; ++r2) pv[r2] = (bf16)(a[r2] + bb);
        *(bf16x4*)(vT + (size_t)(n - 2048) * TT + tB) = pv;  // vT[d][t]
      } else {
        bf16* dst = (seg == 0) ? q : k;
        const int nl = n & 1023;
#pragma unroll
        for (int r2 = 0; r2 < 4; ++r2) dst[(size_t)(tB + r2) * NFD + nl] = (bf16)(a[r2] + bb);
      }
    }
  }
}

// ---- K2: P' = exp(mask(q @ k^T / 32)) as bf16; row sums l via atomicAdd.
//      1D compact triangular grid (528 blocks), band-major, XCD-chunked. ----
__global__ __launch_bounds__(256, 2) void k_scores(const bf16* __restrict__ q, const bf16* __restrict__ kk,
                                                   bf16* __restrict__ P, float* __restrict__ l,
                                                   const int* __restrict__ npadd_p) {
  const int id = blockIdx.x;
  const int lin = (id & 7) * 66 + (id >> 3);
  int band, rem;
  if (lin < 228)      { band = 0; rem = lin; }
  else if (lin < 392) { band = 1; rem = lin - 228; }
  else if (lin < 492) { band = 2; rem = lin - 392; }
  else                { band = 3; rem = lin - 492; }
  int it, jt;
  if (rem < 28) {
    int itp = (int)((sqrtf(8.0f * (float)rem + 1.0f) - 1.0f) * 0.5f);
    while ((itp + 1) * (itp + 2) / 2 <= rem) ++itp;
    while (itp * (itp + 1) / 2 > rem) --itp;
    it = band * 8 + itp;
    jt = band * 8 + (rem - itp * (itp + 1) / 2);
  } else {
    const int rem2 = rem - 28;
    it = band * 8 + 7 + (rem2 >> 3);
    jt = band * 8 + (rem2 & 7);
  }
  const int np = *npadd_p;
  const int jt0 = np >> 7;
  if (jt < jt0) return;

  __shared__ bf16 As[2 * 128 * 32], Bs[2 * 128 * 32];
  const int tid = threadIdx.x;
  f32x4 acc[4][4];
#pragma unroll
  for (int i = 0; i < 4; ++i)
#pragma unroll
    for (int j = 0; j < 4; ++j) acc[i][j] = (f32x4){0.f, 0.f, 0.f, 0.f};

  gemm_core(q + (size_t)it * 128 * CC, kk + (size_t)jt * 128 * CC, CC, CC, CC / 32, As, Bs, tid, acc);

  const int lane = tid & 63;
  const int w = tid >> 6;
  const int wm = (w >> 1) * 64, wn = (w & 1) * 64;
  const float scale = 0.03125f;  // 1/sqrt(1024)
#pragma unroll
  for (int mi = 0; mi < 4; ++mi) {
    const int iB = it * 128 + wm + mi * 16 + ((lane >> 4) << 2);
    float rs[4] = {0.f, 0.f, 0.f, 0.f};
#pragma unroll
    for (int ni = 0; ni < 4; ++ni) {
      const int j = jt * 128 + wn + ni * 16 + (lane & 15);
      f32x4 a = acc[mi][ni];
#pragma unroll
      for (int r = 0; r < 4; ++r) {
        const int i = iB + r;
        float p = 0.f;
        if (j <= i && j >= np && i >= np) p = __expf(a[r] * scale);
        const bf16 pb = (bf16)p;
        P[(size_t)i * TT + j] = pb;
        rs[r] += (float)pb;
      }
    }
#pragma unroll
    for (int r = 0; r < 4; ++r) {
      float v = rs[r];
      v += __shfl_xor(v, 1);
      v += __shfl_xor(v, 2);
      v += __shfl_xor(v, 4);
      v += __shfl_xor(v, 8);
      if ((lane & 15) == 0) atomicAdd(&l[iB + r], v);
    }
  }
}

// ---- K3a: 4-way split-K PV, no atomics, XCD sibling co-location. ----
__global__ __launch_bounds__(256, 2) void k_pvc(const bf16* __restrict__ P, const bf16* __restrict__ vT,
                                                bf16* __restrict__ part0, bf16* __restrict__ part1,
                                                bf16* __restrict__ part2,
                                                const float* __restrict__ l, float* __restrict__ y,
                                                const int* __restrict__ npadd_p) {
  const int id = blockIdx.x;          // 0..1023
  const int kgrp = id >> 3;           // 0..127
  const int d0 = (kgrp & 7) * 128;    // d0 index varies within the sibling window
  const int p = (id & 7) + 8 * (kgrp >> 3);  // pair 0..127, id%8 == p%8 -> same XCD
  const int it = p >> 2;              // 0..31
  const int c = p & 3;                // 0..3
  const int np = *npadd_p;
  const int jt0 = np >> 7;
  const int lo = (c == 0) ? 0 : (c == 1 ? 9 : (c == 2 ? 17 : 25));
  const int hi = (c == 0) ? 9 : (c == 1 ? 17 : (c == 2 ? 25 : 32));
  const int jlo = max(lo, jt0);
  const int jhi = min(hi, it + 1);
  if (jlo >= jhi) return;

  __shared__ bf16 As[2 * 128 * 32], Bs[2 * 128 * 32];
  const int tid = threadIdx.x;
  f32x4 acc[4][4];
#pragma unroll
  for (int i = 0; i < 4; ++i)
#pragma unroll
    for (int j = 0; j < 4; ++j) acc[i][j] = (f32x4){0.f, 0.f, 0.f, 0.f};

  gemm_core(P + (size_t)it * 128 * TT + (size_t)jlo * 128,
            vT + (size_t)d0 * TT + (size_t)jlo * 128,
            TT, TT, (jhi - jlo) * 4, As, Bs, tid, acc);

  const int lane = tid & 63;
  const int w = tid >> 6;
  const int wm = (w >> 1) * 64, wn = (w & 1) * 64;
  const bool sole = (jlo == jt0) && (jhi == it + 1);
  if (sole) {
#pragma unroll
    for (int mi = 0; mi < 4; ++mi) {
      const int iB = it * 128 + wm + mi * 16 + ((lane >> 4) << 2);
      float inv4[4];
#pragma unroll
      for (int r = 0; r < 4; ++r) {
        const int i = iB + r;
        inv4[r] = (i >= np) ? (1.0f / l[i]) : 0.0f;
      }
#pragma unroll
      for (int ni = 0; ni < 4; ++ni) {
        const int d = d0 + wn + ni * 16 + (lane & 15);
        f32x4 a = acc[mi][ni];
#pragma unroll
        for (int r = 0; r < 4; ++r)
          y[(size_t)(iB + r) * NFD + d] = a[r] * inv4[r];
      }
    }
  } else if (c == 3) {
#pragma unroll
    for (int mi = 0; mi < 4; ++mi) {
      const int iB = it * 128 + wm + mi * 16 + ((lane >> 4) << 2);
#pragma unroll
      for (int ni = 0; ni < 4; ++ni) {
        const int d = d0 + wn + ni * 16 + (lane & 15);
        f32x4 a = acc[mi][ni];
#pragma unroll
        for (int r = 0; r < 4; ++r)
          y[(size_t)(iB + r) * NFD + d] = a[r];
      }
    }
  } else {
    bf16* __restrict__ part = (c == 0) ? part0 : (c == 1 ? part1 : part2);
    const int base = (c == 2) ? (PB2 * NFD) : (PB0 * NFD);
#pragma unroll
    for (int mi = 0; mi < 4; ++mi) {
      const int iB = it * 128 + wm + mi * 16 + ((lane >> 4) << 2);
#pragma unroll
      for (int ni = 0; ni < 4; ++ni) {
        const int d = d0 + wn + ni * 16 + (lane & 15);
        f32x4 a = acc[mi][ni];
#pragma unroll
        for (int r = 0; r < 4; ++r)
          part[(size_t)(iB + r) * NFD + d - base] = (bf16)a[r];
      }
    }
  }
}

// ---- K3b: finalize multi-chunk rows: y = (sum of active partials [+ y fp32]) / l. ----
__global__ __launch_bounds__(256) void k_norm(const bf16* __restrict__ part0, const bf16* __restrict__ part1,
                                              const bf16* __restrict__ part2,
                                              const float* __restrict__ l, float* __restrict__ y,
                                              const int* __restrict__ npadd_p) {
  const int idx = (blockIdx.x * 256 + threadIdx.x) * 8;
  const int i = idx >> 10;  // / NFD
  const int np = *npadd_p;
  if (i < np) {
    f32x4 z = (f32x4){0.f, 0.f, 0.f, 0.f};
    *(f32x4*)(y + idx) = z;
    *(f32x4*)(y + idx + 4) = z;
    return;
  }
  const int jt0 = np >> 7;
  const int it = i >> 7;
  const int ip1 = it + 1;
  const bool a0 = (max(0, jt0)  < min(9, ip1));
  const bool a1 = (max(9, jt0)  < min(17, ip1));
  const bool a2 = (max(17, jt0) < min(25, ip1));
  const bool a3 = (max(25, jt0) < min(32, ip1));
  const int cnt = (int)a0 + (int)a1 + (int)a2 + (int)a3;
  if (cnt <= 1) return;  // sole-writer row: y already final
  float s[8] = {0.f, 0.f, 0.f, 0.f, 0.f, 0.f, 0.f, 0.f};
  if (a0) {
    bf16x8 a = *(const bf16x8*)(part0 + idx - PB0 * NFD);
#pragma unroll
    for (int j = 0; j < 8; ++j) s[j] += (float)a[j];
  }
  if (a1) {
    bf16x8 a = *(const bf16x8*)(part1 + idx - PB0 * NFD);
#pragma unroll
    for (int j = 0; j < 8; ++j) s[j] += (float)a[j];
  }
  if (a2) {
    bf16x8 a = *(const bf16x8*)(part2 + idx - PB2 * NFD);
#pragma unroll
    for (int j = 0; j < 8; ++j) s[j] += (float)a[j];
  }
  if (a3) {
    f32x4 a = *(const f32x4*)(y + idx);
    f32x4 b = *(const f32x4*)(y + idx + 4);
#pragma unroll
    for (int j = 0; j < 4; ++j) { s[j] += a[j]; s[4 + j] += b[j]; }
  }
  const float inv = 1.0f / l[i];
  f32x4 o0, o1;
#pragma unroll
  for (int j = 0; j < 4; ++j) { o0[j] = s[j] * inv; o1[j] = s[4 + j] * inv; }
  *(f32x4*)(y + idx) = o0;
  *(f32x4*)(y + idx + 4) = o1;
}

extern "C" void kernel_launch(void* const* d_in, const int* in_sizes, int n_in,
                              void* d_out, int out_size, void* d_ws, size_t ws_size,
                              hipStream_t stream) {
  const float* x = (const float*)d_in[0];
  const float* W = (const float*)d_in[1];
  const float* b = (const float*)d_in[2];
  const int* npadd = (const int*)d_in[3];
  float* y = (float*)d_out;

  char* ws = (char*)d_ws;
  const size_t MB = 1u << 20;
  bf16* q  = (bf16*)(ws + 0 * MB);          // 8 MB  [T][C]   (dead after k_scores)
  bf16* kk = (bf16*)(ws + 8 * MB);          // 8 MB  [T][C]   (dead after k_scores)
  // compact PV partials overlay q/kk (15.25 MB total <= 16 MB):
  bf16* part0 = (bf16*)(ws + 0 * MB);                        // rows [1152,4096)
  bf16* part1 = (bf16*)(ws + (size_t)(TT - PB0) * NFD * 2);  // rows [1152,4096)
  bf16* part2 = (bf16*)(ws + (size_t)2 * (TT - PB0) * NFD * 2);  // rows [2176,4096)
  bf16* vT = (bf16*)(ws + 16 * MB);         // 8 MB  [D][T]
  float* l = (float*)(ws + 24 * MB);        // 16 KB
  bf16* P  = (bf16*)(ws + 24 * MB + 65536); // 32 MB [T][T]
  bf16* xb = P;                              // overlap: dead before K2 writes P
  bf16* WbT = (bf16*)((char*)P + 8 * MB);    // 6 MB, also dead before K2

  // K0: convert x + transpose/convert W + zero l (merged)
  k_prep<<<dim3(2048 + 768 + 1), 256, 0, stream>>>(x, xb, W, WbT, l);
  // K1: QKV projection (1D XCD-chunked grid: XCD owns 4 it-rows x 24 jt)
  k_qkv<<<dim3(768), 256, 0, stream>>>(xb, WbT, b, q, kk, vT);
  // K2: masked exp-scores + row sums (compact triangular grid, XCD-chunked)
  k_scores<<<dim3(528), 256, 0, stream>>>(q, kk, P, l, npadd);
  // K3: 4-way split-K PV, XCD sibling co-location for P-stripe L2 reuse
  k_pvc<<<dim3(1024), 256, 0, stream>>>(P, vT, part0, part1, part2, l, y, npadd);
  // K3b: finalize multi-chunk rows + zero pad rows
  k_norm<<<dim3((TT * NFD) / (256 * 8)), 256, 0, stream>>>(part0, part1, part2, l, y, npadd);
}